// Round 8
// baseline (1974.700 us; speedup 1.0000x reference)
//
#include <hip/hip_runtime.h>

#define NEDGES 1600000
#define NNODES 100000
#define NF 128
#define NSCAN_BLK 98   // ceil(100000/1024)
#define HREP 16        // hist probe amplification
#define FREP 8         // fill probe amplification

typedef short s16x8 __attribute__((ext_vector_type(8)));
typedef float f32x4 __attribute__((ext_vector_type(4)));

// ---- workspace byte layout ----
#define CNT_B    0u          // int[100000]
#define CNT2_B   400000u     // int[100000]   probe dummy
#define CUR2_B   800000u     // int[100000]   probe dummy
#define ROWPTR_B 1200000u    // int[100001]
#define CURSOR_B 1600016u    // int[100000]
#define BSUM_B   2000016u    // int[98] (+pad)
#define WBF_B    2000416u    // ushort[16384]
#define EIDS_B   2033184u    // uint[1600000]
#define EIDS2_B  8433184u    // uint[FREP*1600000] probe dummy (51.2MB)

static __device__ __forceinline__ unsigned short f2bf(float x) {
    unsigned u = __float_as_uint(x);
    return (unsigned short)((u + 0x7fffu + ((u >> 16) & 1u)) >> 16);  // RNE
}

// hist + W->bf16 conversion folded together.
__global__ __launch_bounds__(256) void k_hist(const int* __restrict__ dst,
                                              int* __restrict__ cnt,
                                              const float* __restrict__ W,
                                              unsigned short* __restrict__ Wb) {
    int i = blockIdx.x * 256 + threadIdx.x;
    if (i < NF * NF) Wb[i] = f2bf(W[i]);
    if (i < NEDGES) atomicAdd(&cnt[dst[i]], 1);
}

// PROBE: 16x the hist atomic pattern into a dummy counter array.
__global__ __launch_bounds__(256) void k_hist_probe(const int* __restrict__ dst,
                                                    int* __restrict__ cnt2) {
    int i = blockIdx.x * 256 + threadIdx.x;
    if (i < NEDGES) {
        const int d = dst[i];
        #pragma unroll 1
        for (int r = 0; r < HREP; ++r) atomicAdd(&cnt2[d], 1);
    }
}

__global__ __launch_bounds__(1024) void k_scan1(const int* __restrict__ cnt,
                                                int* __restrict__ rowptr,
                                                int* __restrict__ bsum) {
    const int t = threadIdx.x;
    const int i = blockIdx.x * 1024 + t;
    const int v = (i < NNODES) ? cnt[i] : 0;
    __shared__ int ps[1024];
    ps[t] = v;
    __syncthreads();
    for (int off = 1; off < 1024; off <<= 1) {
        int u = (t >= off) ? ps[t - off] : 0;
        __syncthreads();
        ps[t] += u;
        __syncthreads();
    }
    if (i < NNODES) rowptr[i] = ps[t] - v;
    if (t == 1023) bsum[blockIdx.x] = ps[1023];
}

// scan2+scan3 merged: each block reduces bsum[0..blockIdx.x) itself.
__global__ __launch_bounds__(1024) void k_scan23(int* __restrict__ rowptr,
                                                 const int* __restrict__ bsum,
                                                 int* __restrict__ cursor) {
    const int t = threadIdx.x;
    const int i = blockIdx.x * 1024 + t;
    __shared__ int red[1024];
    red[t] = (t < blockIdx.x) ? bsum[t] : 0;   // blockIdx.x <= 97
    __syncthreads();
    for (int s = 512; s > 0; s >>= 1) {
        if (t < s) red[t] += red[t + s];
        __syncthreads();
    }
    const int off = red[0];
    if (i < NNODES) {
        const int r = rowptr[i] + off;
        rowptr[i] = r;
        cursor[i] = r;
    }
    if (blockIdx.x == 0 && t == 0) rowptr[NNODES] = NEDGES;
}

__global__ __launch_bounds__(256) void k_fill(const int* __restrict__ dst,
                                              int* __restrict__ cursor,
                                              unsigned* __restrict__ eids) {
    int i = blockIdx.x * 256 + threadIdx.x;
    if (i < NEDGES) {
        const int d = dst[i];
        const int p = atomicAdd(&cursor[d], 1);
        eids[p] = ((unsigned)i << 4) | (unsigned)(d & 15);
    }
}

// PROBE: 8x the fill pattern into dummy cursor/eids (results never read).
__global__ __launch_bounds__(256) void k_fill_probe(const int* __restrict__ dst,
                                                    int* __restrict__ cur2,
                                                    unsigned* __restrict__ eids2) {
    int i = blockIdx.x * 256 + threadIdx.x;
    if (i < NEDGES) {
        const int d = dst[i];
        #pragma unroll 1
        for (int r = 0; r < FREP; ++r) {
            const int p = atomicAdd(&cur2[d], 1);
            eids2[p] = ((unsigned)i << 4) | (unsigned)(d & 15);
        }
    }
}

// ---------------------------------------------------------------------------
// Fused gather + mean + (W @ agg + b) + ReLU — R6-verified structure, 399us
// config. Per-wave contiguous chunks, coalesced eids lane-load + readlane
// broadcast (no pointer-chase), 16-deep unconditional 512B load batches,
// segmented REGISTER accumulation, conflict-free LDS flush. Per-edge ds_add
// consumption is the proven-slow path (R3/R5) — do NOT reintroduce.
// ---------------------------------------------------------------------------
__global__ __launch_bounds__(256) void k_fused(
        const float* __restrict__ edge, const int* __restrict__ rowptr,
        const unsigned* __restrict__ eids, const unsigned short* __restrict__ Wb,
        const float* __restrict__ bias, float* __restrict__ out) {
    __shared__ float aggf[16][132];
    __shared__ __align__(16) char aggb[16 * 256];
    const int tid  = threadIdx.x;
    const int lane = tid & 63;
    const int wv   = tid >> 6;
    const int l15  = lane & 15;
    const int l4   = lane >> 4;
    const int n0   = blockIdx.x * 16;

    for (int idx = tid; idx < 16 * 132; idx += 256)
        (&aggf[0][0])[idx] = 0.0f;
    __syncthreads();

    const int eb    = rowptr[n0];
    const int ee    = rowptr[n0 + 16];
    const int chunk = (ee - eb + 3) >> 2;
    const int wcs   = eb + wv * chunk;
    const int wce   = min(wcs + chunk, ee);

    int   cur = -1;
    float a0 = 0.f, a1 = 0.f;

    for (int base = wcs; base < wce; base += 64) {
        const int m = min(64, wce - base);
        const unsigned ev = (lane < m) ? eids[base + lane] : 0u;
        int b = 0;
        for (; b + 16 <= m; b += 16) {
            unsigned id[16];
            int      rw[16];
            #pragma unroll
            for (int j = 0; j < 16; ++j) {
                const unsigned u = (unsigned)__builtin_amdgcn_readlane((int)ev, b + j);
                id[j] = u >> 4;
                rw[j] = (int)(u & 15u);
            }
            float2 xv[16];
            #pragma unroll
            for (int j = 0; j < 16; ++j)
                xv[j] = *(const float2*)(edge + (size_t)id[j] * NF + lane * 2);
            #pragma unroll
            for (int j = 0; j < 16; ++j) {
                if (rw[j] != cur) {            // wave-uniform scalar branch
                    if (cur >= 0) {
                        atomicAdd(&aggf[cur][lane], a0);
                        atomicAdd(&aggf[cur][64 + lane], a1);
                    }
                    cur = rw[j];
                    a0 = 0.f; a1 = 0.f;
                }
                a0 += xv[j].x;
                a1 += xv[j].y;
            }
        }
        for (; b < m; ++b) {
            const unsigned u = (unsigned)__builtin_amdgcn_readlane((int)ev, b);
            const float2 v = *(const float2*)(edge + (size_t)(u >> 4) * NF + lane * 2);
            const int r = (int)(u & 15u);
            if (r != cur) {
                if (cur >= 0) {
                    atomicAdd(&aggf[cur][lane], a0);
                    atomicAdd(&aggf[cur][64 + lane], a1);
                }
                cur = r;
                a0 = 0.f; a1 = 0.f;
            }
            a0 += v.x;
            a1 += v.y;
        }
    }
    if (cur >= 0) {
        atomicAdd(&aggf[cur][lane], a0);
        atomicAdd(&aggf[cur][64 + lane], a1);
    }
    __syncthreads();

    // mean + bf16 pack into XOR-swizzled tile.
    {
        const int r  = tid >> 4;
        const int p0 = (tid & 15) * 4;
        const int cs = rowptr[n0 + r];
        const int ce = rowptr[n0 + r + 1];
        const float inv = 1.0f / fmaxf((float)(ce - cs), 1.0f);
        const float4 xv = *(const float4*)&aggf[r][p0];
        const float4 yv = *(const float4*)&aggf[r][64 + p0];
        const float xa[4] = {xv.x, xv.y, xv.z, xv.w};
        const float ya[4] = {yv.x, yv.y, yv.z, yv.w};
        #pragma unroll
        for (int j = 0; j < 4; ++j) {
            const unsigned pk = (unsigned)f2bf(xa[j] * inv) |
                                ((unsigned)f2bf(ya[j] * inv) << 16);
            const int byt = ((r * 256 + (p0 + j) * 4) ^ ((r & 7) << 4));
            *(unsigned*)(aggb + byt) = pk;
        }
    }
    __syncthreads();

    // MFMA. B[k][n] = W[j0+n][k]; D: col=lane&15, row=(lane>>4)*4+reg (m89).
    #pragma unroll
    for (int t = 0; t < 2; ++t) {
        const int j0 = (wv * 2 + t) * 16;
        f32x4 acc = {0.f, 0.f, 0.f, 0.f};
        #pragma unroll
        for (int ks = 0; ks < 4; ++ks) {
            const s16x8 wfv = *(const s16x8*)((const char*)Wb +
                                              (j0 + l15) * 256 + ks * 64 + l4 * 16);
            const int byt = ((l15 * 256 + ks * 64 + l4 * 16) ^ ((l15 & 7) << 4));
            const s16x8 av = *(const s16x8*)(aggb + byt);
            acc = __builtin_amdgcn_mfma_f32_16x16x32_bf16(av, wfv, acc, 0, 0, 0);
        }
        const float bj = bias[j0 + l15];
        #pragma unroll
        for (int r = 0; r < 4; ++r) {
            const int m = l4 * 4 + r;
            out[(size_t)(n0 + m) * NF + j0 + l15] = fmaxf(acc[r] + bj, 0.f);
        }
    }
}

extern "C" void kernel_launch(void* const* d_in, const int* in_sizes, int n_in,
                              void* d_out, int out_size, void* d_ws, size_t ws_size,
                              hipStream_t stream) {
    const float* edge = (const float*)d_in[0];
    const int*   dst  = (const int*)d_in[1];
    const float* W    = (const float*)d_in[2];
    const float* b    = (const float*)d_in[3];
    float* out = (float*)d_out;

    char* ws = (char*)d_ws;
    int*            cnt    = (int*)(ws + CNT_B);
    int*            cnt2   = (int*)(ws + CNT2_B);
    int*            cur2   = (int*)(ws + CUR2_B);
    int*            rowptr = (int*)(ws + ROWPTR_B);
    int*            cursor = (int*)(ws + CURSOR_B);
    int*            bsum   = (int*)(ws + BSUM_B);
    unsigned short* Wb     = (unsigned short*)(ws + WBF_B);
    unsigned*       eids   = (unsigned*)(ws + EIDS_B);
    unsigned*       eids2  = (unsigned*)(ws + EIDS2_B);

    // zero cnt, cnt2, cur2 in one contiguous memset
    hipMemsetAsync(ws + CNT_B, 0, 1200000, stream);

    k_hist<<<(NEDGES + 255) / 256, 256, 0, stream>>>(dst, cnt, W, Wb);
    k_hist_probe<<<(NEDGES + 255) / 256, 256, 0, stream>>>(dst, cnt2);
    k_scan1<<<NSCAN_BLK, 1024, 0, stream>>>(cnt, rowptr, bsum);
    k_scan23<<<NSCAN_BLK, 1024, 0, stream>>>(rowptr, bsum, cursor);
    k_fill<<<(NEDGES + 255) / 256, 256, 0, stream>>>(dst, cursor, eids);
    k_fill_probe<<<(NEDGES + 255) / 256, 256, 0, stream>>>(dst, cur2, eids2);
    k_fused<<<NNODES / 16, 256, 0, stream>>>(edge, rowptr, eids, Wb, b, out);
}

// Round 9
// 302.987 us; speedup vs baseline: 6.5174x; 6.5174x over previous
//
#include <hip/hip_runtime.h>

#define NEDGES 1600000
#define NNODES 100000
#define NF 128
#define NSCAN_BLK 98   // ceil(100000/1024), 1024 elems per block (int4/thread)

typedef short s16x8 __attribute__((ext_vector_type(8)));
typedef float f32x4 __attribute__((ext_vector_type(4)));

// ---- workspace byte layout ----
#define CNT_B    0u          // int[100000]                 400000 B
#define SST_B    400000u     // u64[98] lookback state      784 B (pad->400800)
#define ROWPTR_B 400800u     // int[100001] (16B aligned)
#define RANK_B   800816u     // int[1600000]
#define EIDS_B   7200816u    // uint[1600000] packed (eid<<4)|(dst&15)
#define WBF_B    13600816u   // ushort[16384]

static __device__ __forceinline__ unsigned short f2bf(float x) {
    unsigned u = __float_as_uint(x);
    return (unsigned short)((u + 0x7fffu + ((u >> 16) & 1u)) >> 16);  // RNE
}

// rank[i] = within-node arrival index (atomic hist that keeps its return
// value — same atomic cost as plain hist, makes k_fill atomic-free).
// W->bf16 conversion folded in.
__global__ __launch_bounds__(256) void k_rank(const int* __restrict__ dst,
                                              int* __restrict__ cnt,
                                              int* __restrict__ rank,
                                              const float* __restrict__ W,
                                              unsigned short* __restrict__ Wb) {
    int i = blockIdx.x * 256 + threadIdx.x;
    if (i < NF * NF) Wb[i] = f2bf(W[i]);
    if (i < NEDGES) rank[i] = atomicAdd(&cnt[dst[i]], 1);
}

// One-dispatch exclusive scan of cnt -> rowptr via decoupled lookback.
// 98 blocks x 256 threads x int4. state[b] = (status<<32)|value, status 1 =
// block aggregate, 2 = inclusive prefix; agent-scope atomics (cross-XCD).
// All 98 blocks are co-resident (98 < 256 CUs) => spin cannot deadlock.
__global__ __launch_bounds__(256) void k_scan(const int* __restrict__ cnt,
                                              int* __restrict__ rowptr,
                                              unsigned long long* __restrict__ state) {
    const int t = threadIdx.x, b = blockIdx.x;
    const int lane = t & 63, wv = t >> 6;
    const int i0 = b * 1024 + t * 4;
    int v0 = 0, v1 = 0, v2 = 0, v3 = 0;
    if (i0 + 4 <= NNODES) {
        const int4 q = *(const int4*)(cnt + i0);
        v0 = q.x; v1 = q.y; v2 = q.z; v3 = q.w;
    } else if (i0 < NNODES) {
        v0 = cnt[i0];
        if (i0 + 1 < NNODES) v1 = cnt[i0 + 1];
        if (i0 + 2 < NNODES) v2 = cnt[i0 + 2];
        if (i0 + 3 < NNODES) v3 = cnt[i0 + 3];
    }
    const int tsum = v0 + v1 + v2 + v3;
    int winc = tsum;                       // wave-inclusive scan of thread sums
    #pragma unroll
    for (int d = 1; d < 64; d <<= 1) {
        const int u = __shfl_up(winc, d, 64);
        if (lane >= d) winc += u;
    }
    __shared__ int wsum[4];
    __shared__ int xbase;
    if (lane == 63) wsum[wv] = winc;
    __syncthreads();
    int woff = 0;
    #pragma unroll
    for (int w = 0; w < 3; ++w)
        if (wv > w) woff += wsum[w];
    const int tot = wsum[0] + wsum[1] + wsum[2] + wsum[3];

    if (t == 0) {
        if (b > 0)
            __hip_atomic_store(&state[b],
                               ((unsigned long long)1 << 32) | (unsigned)tot,
                               __ATOMIC_RELEASE, __HIP_MEMORY_SCOPE_AGENT);
        int excl = 0;
        for (int p = b - 1; p >= 0; --p) {
            unsigned long long s;
            do {
                s = __hip_atomic_load(&state[p], __ATOMIC_ACQUIRE,
                                      __HIP_MEMORY_SCOPE_AGENT);
                if (!(s >> 32)) __builtin_amdgcn_s_sleep(8);
            } while (!(s >> 32));
            excl += (int)(unsigned)s;
            if ((s >> 32) == 2) break;
        }
        __hip_atomic_store(&state[b],
                           ((unsigned long long)2 << 32) | (unsigned)(excl + tot),
                           __ATOMIC_RELEASE, __HIP_MEMORY_SCOPE_AGENT);
        xbase = excl;
    }
    __syncthreads();

    const int base = xbase + woff + (winc - tsum);   // exclusive prefix at i0
    if (i0 + 4 <= NNODES) {
        int4 r;
        r.x = base; r.y = base + v0; r.z = base + v0 + v1; r.w = base + v0 + v1 + v2;
        *(int4*)(rowptr + i0) = r;
    } else if (i0 < NNODES) {
        rowptr[i0] = base;
        if (i0 + 1 < NNODES) rowptr[i0 + 1] = base + v0;
        if (i0 + 2 < NNODES) rowptr[i0 + 2] = base + v0 + v1;
        if (i0 + 3 < NNODES) rowptr[i0 + 3] = base + v0 + v1 + v2;
    }
    if (b == 0 && t == 0) rowptr[NNODES] = NEDGES;
}

// Atomic-free CSR fill: position = rowptr[d] + rank[i], plain store.
__global__ __launch_bounds__(256) void k_fill(const int* __restrict__ dst,
                                              const int* __restrict__ rowptr,
                                              const int* __restrict__ rank,
                                              unsigned* __restrict__ eids) {
    int i = blockIdx.x * 256 + threadIdx.x;
    if (i < NEDGES) {
        const int d = dst[i];
        eids[rowptr[d] + rank[i]] = ((unsigned)i << 4) | (unsigned)(d & 15);
    }
}

// ---------------------------------------------------------------------------
// Fused gather + mean + (W @ agg + b) + ReLU — R6-verified structure (399us).
// Per-wave contiguous chunks, coalesced eids lane-load + readlane broadcast
// (no pointer-chase), 16-deep unconditional 512B load batches, segmented
// REGISTER accumulation, conflict-free LDS flush. Per-edge ds_add consumption
// is the proven-slow path (R3/R5: ~5x regression) — do NOT reintroduce.
// ---------------------------------------------------------------------------
__global__ __launch_bounds__(256) void k_fused(
        const float* __restrict__ edge, const int* __restrict__ rowptr,
        const unsigned* __restrict__ eids, const unsigned short* __restrict__ Wb,
        const float* __restrict__ bias, float* __restrict__ out) {
    __shared__ float aggf[16][132];
    __shared__ __align__(16) char aggb[16 * 256];
    const int tid  = threadIdx.x;
    const int lane = tid & 63;
    const int wv   = tid >> 6;
    const int l15  = lane & 15;
    const int l4   = lane >> 4;
    const int n0   = blockIdx.x * 16;

    for (int idx = tid; idx < 16 * 132; idx += 256)
        (&aggf[0][0])[idx] = 0.0f;
    __syncthreads();

    const int eb    = rowptr[n0];
    const int ee    = rowptr[n0 + 16];
    const int chunk = (ee - eb + 3) >> 2;
    const int wcs   = eb + wv * chunk;
    const int wce   = min(wcs + chunk, ee);

    int   cur = -1;
    float a0 = 0.f, a1 = 0.f;

    for (int base = wcs; base < wce; base += 64) {
        const int m = min(64, wce - base);
        const unsigned ev = (lane < m) ? eids[base + lane] : 0u;
        int b = 0;
        for (; b + 16 <= m; b += 16) {
            unsigned id[16];
            int      rw[16];
            #pragma unroll
            for (int j = 0; j < 16; ++j) {
                const unsigned u = (unsigned)__builtin_amdgcn_readlane((int)ev, b + j);
                id[j] = u >> 4;
                rw[j] = (int)(u & 15u);
            }
            float2 xv[16];
            #pragma unroll
            for (int j = 0; j < 16; ++j)
                xv[j] = *(const float2*)(edge + (size_t)id[j] * NF + lane * 2);
            #pragma unroll
            for (int j = 0; j < 16; ++j) {
                if (rw[j] != cur) {            // wave-uniform scalar branch
                    if (cur >= 0) {
                        atomicAdd(&aggf[cur][lane], a0);
                        atomicAdd(&aggf[cur][64 + lane], a1);
                    }
                    cur = rw[j];
                    a0 = 0.f; a1 = 0.f;
                }
                a0 += xv[j].x;
                a1 += xv[j].y;
            }
        }
        for (; b < m; ++b) {
            const unsigned u = (unsigned)__builtin_amdgcn_readlane((int)ev, b);
            const float2 v = *(const float2*)(edge + (size_t)(u >> 4) * NF + lane * 2);
            const int r = (int)(u & 15u);
            if (r != cur) {
                if (cur >= 0) {
                    atomicAdd(&aggf[cur][lane], a0);
                    atomicAdd(&aggf[cur][64 + lane], a1);
                }
                cur = r;
                a0 = 0.f; a1 = 0.f;
            }
            a0 += v.x;
            a1 += v.y;
        }
    }
    if (cur >= 0) {
        atomicAdd(&aggf[cur][lane], a0);
        atomicAdd(&aggf[cur][64 + lane], a1);
    }
    __syncthreads();

    // mean + bf16 pack into XOR-swizzled tile.
    {
        const int r  = tid >> 4;
        const int p0 = (tid & 15) * 4;
        const int cs = rowptr[n0 + r];
        const int ce = rowptr[n0 + r + 1];
        const float inv = 1.0f / fmaxf((float)(ce - cs), 1.0f);
        const float4 xv = *(const float4*)&aggf[r][p0];
        const float4 yv = *(const float4*)&aggf[r][64 + p0];
        const float xa[4] = {xv.x, xv.y, xv.z, xv.w};
        const float ya[4] = {yv.x, yv.y, yv.z, yv.w};
        #pragma unroll
        for (int j = 0; j < 4; ++j) {
            const unsigned pk = (unsigned)f2bf(xa[j] * inv) |
                                ((unsigned)f2bf(ya[j] * inv) << 16);
            const int byt = ((r * 256 + (p0 + j) * 4) ^ ((r & 7) << 4));
            *(unsigned*)(aggb + byt) = pk;
        }
    }
    __syncthreads();

    // MFMA. B[k][n] = W[j0+n][k]; D: col=lane&15, row=(lane>>4)*4+reg (m89).
    #pragma unroll
    for (int t = 0; t < 2; ++t) {
        const int j0 = (wv * 2 + t) * 16;
        f32x4 acc = {0.f, 0.f, 0.f, 0.f};
        #pragma unroll
        for (int ks = 0; ks < 4; ++ks) {
            const s16x8 wfv = *(const s16x8*)((const char*)Wb +
                                              (j0 + l15) * 256 + ks * 64 + l4 * 16);
            const int byt = ((l15 * 256 + ks * 64 + l4 * 16) ^ ((l15 & 7) << 4));
            const s16x8 av = *(const s16x8*)(aggb + byt);
            acc = __builtin_amdgcn_mfma_f32_16x16x32_bf16(av, wfv, acc, 0, 0, 0);
        }
        const float bj = bias[j0 + l15];
        #pragma unroll
        for (int r = 0; r < 4; ++r) {
            const int m = l4 * 4 + r;
            out[(size_t)(n0 + m) * NF + j0 + l15] = fmaxf(acc[r] + bj, 0.f);
        }
    }
}

extern "C" void kernel_launch(void* const* d_in, const int* in_sizes, int n_in,
                              void* d_out, int out_size, void* d_ws, size_t ws_size,
                              hipStream_t stream) {
    const float* edge = (const float*)d_in[0];
    const int*   dst  = (const int*)d_in[1];
    const float* W    = (const float*)d_in[2];
    const float* b    = (const float*)d_in[3];
    float* out = (float*)d_out;

    char* ws = (char*)d_ws;
    int*                cnt    = (int*)(ws + CNT_B);
    unsigned long long* sstate = (unsigned long long*)(ws + SST_B);
    int*                rowptr = (int*)(ws + ROWPTR_B);
    int*                rank   = (int*)(ws + RANK_B);
    unsigned*           eids   = (unsigned*)(ws + EIDS_B);
    unsigned short*     Wb     = (unsigned short*)(ws + WBF_B);

    // zero cnt + lookback state in one memset (re-done every call/replay)
    hipMemsetAsync(ws + CNT_B, 0, 400800, stream);

    k_rank<<<(NEDGES + 255) / 256, 256, 0, stream>>>(dst, cnt, rank, W, Wb);
    k_scan<<<NSCAN_BLK, 256, 0, stream>>>(cnt, rowptr, sstate);
    k_fill<<<(NEDGES + 255) / 256, 256, 0, stream>>>(dst, rowptr, rank, eids);
    k_fused<<<NNODES / 16, 256, 0, stream>>>(edge, rowptr, eids, Wb, b, out);
}

// Round 11
// 293.924 us; speedup vs baseline: 6.7184x; 1.0308x over previous
//
#include <hip/hip_runtime.h>

#define NEDGES 1600000
#define NNODES 100000
#define NF 128
#define NSCAN_BLK 98   // ceil(100000/1024), 1024 elems per block (int4/thread)

typedef short s16x8 __attribute__((ext_vector_type(8)));
typedef float f32x4 __attribute__((ext_vector_type(4)));

// ---- workspace byte layout ----
#define CNT_B    0u          // int[100000]                 400000 B
#define SST_B    400000u     // u64[98] lookback state      784 B (pad->400800)
#define ROWPTR_B 400800u     // int[100001] (16B aligned)
#define RANK_B   800816u     // int[1600000]
#define EIDS_B   7200816u    // uint[1600000] packed (eid<<4)|(dst&15)
#define WBF_B    13600816u   // ushort[16384]

static __device__ __forceinline__ unsigned short f2bf(float x) {
    unsigned u = __float_as_uint(x);
    return (unsigned short)((u + 0x7fffu + ((u >> 16) & 1u)) >> 16);  // RNE
}

// rank[i] = within-node arrival index; doubles as the histogram (atomic
// return value kept => k_fill needs no atomics). 4 edges/thread, int4 I/O.
// W->bf16 conversion folded in.
__global__ __launch_bounds__(256) void k_rank(const int* __restrict__ dst,
                                              int* __restrict__ cnt,
                                              int* __restrict__ rank,
                                              const float* __restrict__ W,
                                              unsigned short* __restrict__ Wb) {
    const int t = blockIdx.x * 256 + threadIdx.x;
    if (t < NF * NF) Wb[t] = f2bf(W[t]);
    const int i = t * 4;
    if (i + 4 <= NEDGES) {
        const int4 d = *(const int4*)(dst + i);
        int4 r;
        r.x = atomicAdd(&cnt[d.x], 1);
        r.y = atomicAdd(&cnt[d.y], 1);
        r.z = atomicAdd(&cnt[d.z], 1);
        r.w = atomicAdd(&cnt[d.w], 1);
        *(int4*)(rank + i) = r;
    }
}

// One-dispatch exclusive scan of cnt -> rowptr via decoupled lookback with
// WAVE-PARALLEL lookback (lane l inspects state[b-1-l]). status 1 =
// aggregate, 2 = inclusive prefix. R10 BUG FIXED: when a window has NO
// status-2 entry (m2==0), consume ALL 64 aggregates (f=63), not zero.
// All 98 blocks co-resident (98 < 256 CUs) => spin cannot deadlock.
__global__ __launch_bounds__(256) void k_scan(const int* __restrict__ cnt,
                                              int* __restrict__ rowptr,
                                              unsigned long long* __restrict__ state) {
    const int t = threadIdx.x, b = blockIdx.x;
    const int lane = t & 63, wv = t >> 6;
    const int i0 = b * 1024 + t * 4;
    int v0 = 0, v1 = 0, v2 = 0, v3 = 0;
    if (i0 + 4 <= NNODES) {
        const int4 q = *(const int4*)(cnt + i0);
        v0 = q.x; v1 = q.y; v2 = q.z; v3 = q.w;
    } else if (i0 < NNODES) {
        v0 = cnt[i0];
        if (i0 + 1 < NNODES) v1 = cnt[i0 + 1];
        if (i0 + 2 < NNODES) v2 = cnt[i0 + 2];
    }
    const int tsum = v0 + v1 + v2 + v3;
    int winc = tsum;                       // wave-inclusive scan of thread sums
    #pragma unroll
    for (int d = 1; d < 64; d <<= 1) {
        const int u = __shfl_up(winc, d, 64);
        if (lane >= d) winc += u;
    }
    __shared__ int wsum[4];
    __shared__ int xbase;
    if (lane == 63) wsum[wv] = winc;
    __syncthreads();
    int woff = 0;
    #pragma unroll
    for (int w = 0; w < 3; ++w)
        if (wv > w) woff += wsum[w];
    const int tot = wsum[0] + wsum[1] + wsum[2] + wsum[3];

    if (wv == 0) {                          // wave 0: publish + parallel lookback
        if (b > 0) {
            if (lane == 0)
                __hip_atomic_store(&state[b],
                                   ((unsigned long long)1 << 32) | (unsigned)tot,
                                   __ATOMIC_RELEASE, __HIP_MEMORY_SCOPE_AGENT);
            int excl = 0;
            int p = b - 1;                  // window covers blocks p-lane
            for (;;) {
                const int idx = p - lane;
                unsigned long long s;
                do {                        // spin until whole window is valid
                    s = (idx >= 0)
                        ? __hip_atomic_load(&state[idx], __ATOMIC_ACQUIRE,
                                            __HIP_MEMORY_SCOPE_AGENT)
                        : ((unsigned long long)2 << 32);   // OOB: prefix 0
                    if (!(s >> 32)) __builtin_amdgcn_s_sleep(2);
                } while (__any(!(s >> 32)));
                const unsigned long long m2 = __ballot((s >> 32) == 2);
                // nearest status-2 if any; else consume the WHOLE window
                const int f = m2 ? (__ffsll((long long)m2) - 1) : 63;
                int c = (lane <= f) ? (int)(unsigned)s : 0;
                #pragma unroll
                for (int d = 32; d > 0; d >>= 1) c += __shfl_xor(c, d, 64);
                excl += c;
                if (m2) break;
                p -= 64;                    // whole window was aggregates
            }
            if (lane == 0) {
                __hip_atomic_store(&state[b],
                                   ((unsigned long long)2 << 32) |
                                       (unsigned)(excl + tot),
                                   __ATOMIC_RELEASE, __HIP_MEMORY_SCOPE_AGENT);
                xbase = excl;
            }
        } else {
            if (lane == 0) {
                __hip_atomic_store(&state[0],
                                   ((unsigned long long)2 << 32) | (unsigned)tot,
                                   __ATOMIC_RELEASE, __HIP_MEMORY_SCOPE_AGENT);
                xbase = 0;
            }
        }
    }
    __syncthreads();

    const int base = xbase + woff + (winc - tsum);   // exclusive prefix at i0
    if (i0 + 4 <= NNODES) {
        int4 r;
        r.x = base; r.y = base + v0; r.z = base + v0 + v1; r.w = base + v0 + v1 + v2;
        *(int4*)(rowptr + i0) = r;
    } else if (i0 < NNODES) {
        rowptr[i0] = base;
        if (i0 + 1 < NNODES) rowptr[i0 + 1] = base + v0;
        if (i0 + 2 < NNODES) rowptr[i0 + 2] = base + v0 + v1;
    }
    if (b == 0 && t == 0) rowptr[NNODES] = NEDGES;
}

// Atomic-free CSR fill: position = rowptr[d] + rank[i]. 4 edges/thread.
__global__ __launch_bounds__(256) void k_fill(const int* __restrict__ dst,
                                              const int* __restrict__ rowptr,
                                              const int* __restrict__ rank,
                                              unsigned* __restrict__ eids) {
    const int i = (blockIdx.x * 256 + threadIdx.x) * 4;
    if (i + 4 <= NEDGES) {
        const int4 d = *(const int4*)(dst + i);
        const int4 r = *(const int4*)(rank + i);
        eids[rowptr[d.x] + r.x] = ((unsigned)(i + 0) << 4) | (unsigned)(d.x & 15);
        eids[rowptr[d.y] + r.y] = ((unsigned)(i + 1) << 4) | (unsigned)(d.y & 15);
        eids[rowptr[d.z] + r.z] = ((unsigned)(i + 2) << 4) | (unsigned)(d.z & 15);
        eids[rowptr[d.w] + r.w] = ((unsigned)(i + 3) << 4) | (unsigned)(d.w & 15);
    }
}

// ---------------------------------------------------------------------------
// Fused gather + mean + (W @ agg + b) + ReLU — R6-verified structure (399us).
// Per-wave contiguous chunks, coalesced eids lane-load + readlane broadcast
// (no pointer-chase), 16-deep unconditional 512B load batches, segmented
// REGISTER accumulation, conflict-free LDS flush. Per-edge ds_add consumption
// is the proven-slow path (R3/R5: ~5x regression) — do NOT reintroduce.
// ---------------------------------------------------------------------------
__global__ __launch_bounds__(256) void k_fused(
        const float* __restrict__ edge, const int* __restrict__ rowptr,
        const unsigned* __restrict__ eids, const unsigned short* __restrict__ Wb,
        const float* __restrict__ bias, float* __restrict__ out) {
    __shared__ float aggf[16][132];
    __shared__ __align__(16) char aggb[16 * 256];
    const int tid  = threadIdx.x;
    const int lane = tid & 63;
    const int wv   = tid >> 6;
    const int l15  = lane & 15;
    const int l4   = lane >> 4;
    const int n0   = blockIdx.x * 16;

    for (int idx = tid; idx < 16 * 132; idx += 256)
        (&aggf[0][0])[idx] = 0.0f;
    __syncthreads();

    const int eb    = rowptr[n0];
    const int ee    = rowptr[n0 + 16];
    const int chunk = (ee - eb + 3) >> 2;
    const int wcs   = eb + wv * chunk;
    const int wce   = min(wcs + chunk, ee);

    int   cur = -1;
    float a0 = 0.f, a1 = 0.f;

    for (int base = wcs; base < wce; base += 64) {
        const int m = min(64, wce - base);
        const unsigned ev = (lane < m) ? eids[base + lane] : 0u;
        int b = 0;
        for (; b + 16 <= m; b += 16) {
            unsigned id[16];
            int      rw[16];
            #pragma unroll
            for (int j = 0; j < 16; ++j) {
                const unsigned u = (unsigned)__builtin_amdgcn_readlane((int)ev, b + j);
                id[j] = u >> 4;
                rw[j] = (int)(u & 15u);
            }
            float2 xv[16];
            #pragma unroll
            for (int j = 0; j < 16; ++j)
                xv[j] = *(const float2*)(edge + (size_t)id[j] * NF + lane * 2);
            #pragma unroll
            for (int j = 0; j < 16; ++j) {
                if (rw[j] != cur) {            // wave-uniform scalar branch
                    if (cur >= 0) {
                        atomicAdd(&aggf[cur][lane], a0);
                        atomicAdd(&aggf[cur][64 + lane], a1);
                    }
                    cur = rw[j];
                    a0 = 0.f; a1 = 0.f;
                }
                a0 += xv[j].x;
                a1 += xv[j].y;
            }
        }
        for (; b < m; ++b) {
            const unsigned u = (unsigned)__builtin_amdgcn_readlane((int)ev, b);
            const float2 v = *(const float2*)(edge + (size_t)(u >> 4) * NF + lane * 2);
            const int r = (int)(u & 15u);
            if (r != cur) {
                if (cur >= 0) {
                    atomicAdd(&aggf[cur][lane], a0);
                    atomicAdd(&aggf[cur][64 + lane], a1);
                }
                cur = r;
                a0 = 0.f; a1 = 0.f;
            }
            a0 += v.x;
            a1 += v.y;
        }
    }
    if (cur >= 0) {
        atomicAdd(&aggf[cur][lane], a0);
        atomicAdd(&aggf[cur][64 + lane], a1);
    }
    __syncthreads();

    // mean + bf16 pack into XOR-swizzled tile.
    {
        const int r  = tid >> 4;
        const int p0 = (tid & 15) * 4;
        const int cs = rowptr[n0 + r];
        const int ce = rowptr[n0 + r + 1];
        const float inv = 1.0f / fmaxf((float)(ce - cs), 1.0f);
        const float4 xv = *(const float4*)&aggf[r][p0];
        const float4 yv = *(const float4*)&aggf[r][64 + p0];
        const float xa[4] = {xv.x, xv.y, xv.z, xv.w};
        const float ya[4] = {yv.x, yv.y, yv.z, yv.w};
        #pragma unroll
        for (int j = 0; j < 4; ++j) {
            const unsigned pk = (unsigned)f2bf(xa[j] * inv) |
                                ((unsigned)f2bf(ya[j] * inv) << 16);
            const int byt = ((r * 256 + (p0 + j) * 4) ^ ((r & 7) << 4));
            *(unsigned*)(aggb + byt) = pk;
        }
    }
    __syncthreads();

    // MFMA. B[k][n] = W[j0+n][k]; D: col=lane&15, row=(lane>>4)*4+reg (m89).
    #pragma unroll
    for (int t = 0; t < 2; ++t) {
        const int j0 = (wv * 2 + t) * 16;
        f32x4 acc = {0.f, 0.f, 0.f, 0.f};
        #pragma unroll
        for (int ks = 0; ks < 4; ++ks) {
            const s16x8 wfv = *(const s16x8*)((const char*)Wb +
                                              (j0 + l15) * 256 + ks * 64 + l4 * 16);
            const int byt = ((l15 * 256 + ks * 64 + l4 * 16) ^ ((l15 & 7) << 4));
            const s16x8 av = *(const s16x8*)(aggb + byt);
            acc = __builtin_amdgcn_mfma_f32_16x16x32_bf16(av, wfv, acc, 0, 0, 0);
        }
        const float bj = bias[j0 + l15];
        #pragma unroll
        for (int r = 0; r < 4; ++r) {
            const int m = l4 * 4 + r;
            out[(size_t)(n0 + m) * NF + j0 + l15] = fmaxf(acc[r] + bj, 0.f);
        }
    }
}

extern "C" void kernel_launch(void* const* d_in, const int* in_sizes, int n_in,
                              void* d_out, int out_size, void* d_ws, size_t ws_size,
                              hipStream_t stream) {
    const float* edge = (const float*)d_in[0];
    const int*   dst  = (const int*)d_in[1];
    const float* W    = (const float*)d_in[2];
    const float* b    = (const float*)d_in[3];
    float* out = (float*)d_out;

    char* ws = (char*)d_ws;
    int*                cnt    = (int*)(ws + CNT_B);
    unsigned long long* sstate = (unsigned long long*)(ws + SST_B);
    int*                rowptr = (int*)(ws + ROWPTR_B);
    int*                rank   = (int*)(ws + RANK_B);
    unsigned*           eids   = (unsigned*)(ws + EIDS_B);
    unsigned short*     Wb     = (unsigned short*)(ws + WBF_B);

    // zero cnt + lookback state in one memset (re-done every call/replay)
    hipMemsetAsync(ws + CNT_B, 0, 400800, stream);

    k_rank<<<(NEDGES / 4 + 255) / 256, 256, 0, stream>>>(dst, cnt, rank, W, Wb);
    k_scan<<<NSCAN_BLK, 256, 0, stream>>>(cnt, rowptr, sstate);
    k_fill<<<(NEDGES / 4 + 255) / 256, 256, 0, stream>>>(dst, rowptr, rank, eids);
    k_fused<<<NNODES / 16, 256, 0, stream>>>(edge, rowptr, eids, Wb, b, out);
}